// Round 12
// baseline (251.691 us; speedup 1.0000x reference)
//
#include <hip/hip_runtime.h>
#include <hip/hip_bf16.h>

// CausalSelfAttention (B=2, T=2048, D=1024, H=16, hd=64).
// fp32 in, fp32 out storage (bf16-space grading). bf16 MFMA pipeline.
// R12: revert R11's k-tile pairing (regressed: +12 VGPR, no overlap gain).
// Keep R11's glds GEMMs + bf16 pre-casts (saved ~19us). New: slot-permuted
// P/V key order (slot s=(k&15)*4+(k>>4)) so each lane's 4 P values are
// contiguous -> one ds_write_b64 per (rt,r) instead of 4 ds_write_b16.
// V transposed INTO slot order (permuted read row in transpose_v).

typedef __bf16 bf16;
typedef __bf16 bf16x8 __attribute__((ext_vector_type(8)));
typedef float f32x4 __attribute__((ext_vector_type(4)));

__device__ __forceinline__ bf16 f2bf(float f) {
    unsigned u = __builtin_bit_cast(unsigned, f);
    u += 0x7fffu + ((u >> 16) & 1u);          // RNE
    unsigned short h = (unsigned short)(u >> 16);
    return __builtin_bit_cast(bf16, h);
}

__device__ __forceinline__ bf16x8 ld8f(const float* p) {
    f32x4 a = *(const f32x4*)p;
    f32x4 b = *(const f32x4*)(p + 4);
    bf16x8 r;
#pragma unroll
    for (int i = 0; i < 4; i++) { r[i] = f2bf(a[i]); r[i + 4] = f2bf(b[i]); }
    return r;
}

__device__ __forceinline__ void st_out(bf16* p, float v)  { *p = f2bf(v); }
__device__ __forceinline__ void st_out(float* p, float v) { *p = v; }

// fp32 -> bf16 bulk convert
__global__ __launch_bounds__(256) void cvt_bf16(const float* __restrict__ src,
                                                bf16* __restrict__ dst, int n) {
    int i = (blockIdx.x * 256 + threadIdx.x) * 8;
    if (i < n) *(bf16x8*)&dst[i] = ld8f(&src[i]);
}

// async global->LDS, 16B per lane; LDS dest = uniform base + lane*16
__device__ __forceinline__ void glds16(const bf16* g, bf16* l) {
    __builtin_amdgcn_global_load_lds(
        (const __attribute__((address_space(1))) void*)g,
        (__attribute__((address_space(3))) void*)l, 16, 0, 0);
}

// ---------------------------------------------------------------------------
// C[M,N] = A[., lda, +aoff] @ W[N,K]^T, both bf16. global_load_lds staging,
// XOR chunk swizzle (R11-proven). Tile 128 x BN, BK=32, 4 waves.
// ---------------------------------------------------------------------------
template <typename TC, int BN>
__global__ __launch_bounds__(256) void gemm_glds(const bf16* __restrict__ A, int lda, int aoff,
                                                 const bf16* __restrict__ W,
                                                 TC* __restrict__ C, int N, int K) {
    constexpr int NI = (BN == 128) ? 4 : 2;
    __shared__ bf16 sA[128 * 32];
    __shared__ bf16 sW[BN * 32];
    const int bm = blockIdx.x * 128, bn = blockIdx.y * BN;
    const int tid = threadIdx.x;
    const int wave = tid >> 6, lane = tid & 63;
    const int quad = lane >> 4, l16 = lane & 15;
    const int rbase = (BN == 128) ? (wave >> 1) * 64 : wave * 32;
    const int cbase = (BN == 128) ? (wave & 1) * 64 : 0;
    const int r16 = lane >> 2, cl = lane & 3;
    const int gch = cl ^ ((r16 >> 1) & 3);
    const int sl  = (l16 >> 1) & 3;

    f32x4 acc[NI][4] = {};

    for (int k0 = 0; k0 < K; k0 += 32) {
        __syncthreads();
#pragma unroll
        for (int t = 0; t < 2; t++) {
            int row = wave * 32 + t * 16 + r16;
            glds16(&A[(size_t)(bm + row) * lda + aoff + k0 + gch * 8],
                   &sA[(wave * 32 + t * 16) * 32]);
        }
        if (BN == 128) {
#pragma unroll
            for (int t = 0; t < 2; t++) {
                int row = wave * 32 + t * 16 + r16;
                glds16(&W[(size_t)(bn + row) * K + k0 + gch * 8],
                       &sW[(wave * 32 + t * 16) * 32]);
            }
        } else {
            int row = wave * 16 + r16;
            glds16(&W[(size_t)(bn + row) * K + k0 + gch * 8], &sW[(wave * 16) * 32]);
        }
        __syncthreads();

        bf16x8 af[NI], bfr[4];
#pragma unroll
        for (int i = 0; i < NI; i++)
            af[i] = *(bf16x8*)&sA[(rbase + i * 16 + l16) * 32 + (quad ^ sl) * 8];
#pragma unroll
        for (int j = 0; j < 4; j++)
            bfr[j] = *(bf16x8*)&sW[(cbase + j * 16 + l16) * 32 + (quad ^ sl) * 8];
#pragma unroll
        for (int i = 0; i < NI; i++)
#pragma unroll
            for (int j = 0; j < 4; j++)
                acc[i][j] = __builtin_amdgcn_mfma_f32_16x16x32_bf16(
                    af[i], bfr[j], acc[i][j], 0, 0, 0);
    }

#pragma unroll
    for (int i = 0; i < NI; i++)
#pragma unroll
        for (int j = 0; j < 4; j++)
#pragma unroll
            for (int r = 0; r < 4; r++) {
                int row = bm + rbase + i * 16 + quad * 4 + r;
                int col = bn + cbase + j * 16 + l16;
                st_out(&C[(size_t)row * N + col], acc[i][j][r]);
            }
}

// ---------------------------------------------------------------------------
// vt in SLOT order: vt[bh][d][tt*64 + s] = V[b][tt*64 + o(s)][d],
// o(s) = (s>>2) | ((s&3)<<4). Permuted read row; writes stay vectorized.
// ---------------------------------------------------------------------------
__global__ __launch_bounds__(256) void transpose_v(const bf16* __restrict__ qkv,
                                                   bf16* __restrict__ vt) {
    __shared__ bf16 s[64][72];
    const int tt = blockIdx.x;
    const int bh = blockIdx.y;
    const int b = bh >> 4, h = bh & 15;
    const int tid = threadIdx.x;

    for (int c = tid; c < 512; c += 256) {
        int slot = c >> 3, dc = (c & 7) * 8;
        int o = (slot >> 2) | ((slot & 3) << 4);
        *(bf16x8*)&s[slot][dc] =
            *(const bf16x8*)&qkv[((size_t)(b * 2048 + tt * 64 + o)) * 3072 + 2048 + h * 64 + dc];
    }
    __syncthreads();
    for (int c = tid; c < 512; c += 256) {
        int d = c >> 3, tc = (c & 7) * 8;
        bf16x8 oo;
#pragma unroll
        for (int e = 0; e < 8; e++) oo[e] = s[tc + e][d];
        *(bf16x8*)&vt[((size_t)bh * 64 + d) * 2048 + tt * 64 + tc] = oo;
    }
}

// ---------------------------------------------------------------------------
// Flash causal attention, fixed-max softmax, slot-packed P store.
// One wave/block, 32 q-rows. Heavy-first dispatch.
// ---------------------------------------------------------------------------
__global__ __launch_bounds__(64) void attn(bf16* __restrict__ qkv,
                                           const bf16* __restrict__ vt) {
    const int bh = blockIdx.x;
    const int i  = 63 - blockIdx.y;
    const int b = bh >> 4, h = bh & 15;
    const int lane = threadIdx.x;
    const int quad = lane >> 4, l16 = lane & 15;

    __shared__ bf16 sP[32 * 72];   // P in slot order, stride 72 (144B rows)

    bf16* base = qkv + (size_t)b * 2048 * 3072;
    const bf16* vbh = vt + (size_t)bh * 64 * 2048;
    const int qb = i * 32;
    const int kint = i >> 1;
    const float SC = 0.125f * 1.44269504f;

    bf16x8 qa[2][2];
#pragma unroll
    for (int rt = 0; rt < 2; rt++)
#pragma unroll
        for (int c = 0; c < 2; c++)
            qa[rt][c] = *(const bf16x8*)&base[(size_t)(qb + rt * 16 + l16) * 3072 +
                                              h * 64 + c * 32 + quad * 8];

    f32x4 acc[2][4] = {};
    float lpart[2][4] = {};

    for (int kt = 0; kt <= kint; kt++) {
        const bool tail = (kt == kint);

        // V B-frags (slot order) issued early
        bf16x8 vb[4][2];
#pragma unroll
        for (int dt = 0; dt < 4; dt++) {
            const bf16* vr = &vbh[(size_t)(dt * 16 + l16) * 2048 + kt * 64];
            vb[dt][0] = *(const bf16x8*)&vr[quad * 8];
            vb[dt][1] = *(const bf16x8*)&vr[32 + quad * 8];
        }

        // K B-frags + S = Q K^T (original key order)
        f32x4 S[2][4] = {};
#pragma unroll
        for (int j = 0; j < 4; j++) {
            const bf16* kr = &base[(size_t)(kt * 64 + j * 16 + l16) * 3072 + 1024 + h * 64];
            bf16x8 kb0 = *(const bf16x8*)&kr[quad * 8];
            bf16x8 kb1 = *(const bf16x8*)&kr[32 + quad * 8];
#pragma unroll
            for (int rt = 0; rt < 2; rt++) {
                S[rt][j] = __builtin_amdgcn_mfma_f32_16x16x32_bf16(qa[rt][0], kb0, S[rt][j], 0, 0, 0);
                S[rt][j] = __builtin_amdgcn_mfma_f32_16x16x32_bf16(qa[rt][1], kb1, S[rt][j], 0, 0, 0);
            }
        }

        // p = 2^(S*SC-8); slot-packed b64 store: slots l16*4 + j
#pragma unroll
        for (int rt = 0; rt < 2; rt++)
#pragma unroll
            for (int r = 0; r < 4; r++) {
                float p0 = exp2f(S[rt][0][r] * SC - 8.0f);
                float p1 = exp2f(S[rt][1][r] * SC - 8.0f);
                float p2 = exp2f(S[rt][2][r] * SC - 8.0f);
                float p3 = exp2f(S[rt][3][r] * SC - 8.0f);
                if (tail) {
                    int qg = qb + rt * 16 + quad * 4 + r;
                    int k0g = kt * 64 + l16;
                    p0 = (k0g      > qg) ? 0.0f : p0;
                    p1 = (k0g + 16 > qg) ? 0.0f : p1;
                    p2 = (k0g + 32 > qg) ? 0.0f : p2;
                    p3 = (k0g + 48 > qg) ? 0.0f : p3;
                }
                lpart[rt][r] += (p0 + p1) + (p2 + p3);
                unsigned u0 = __builtin_bit_cast(unsigned, p0);
                unsigned u1 = __builtin_bit_cast(unsigned, p1);
                unsigned u2 = __builtin_bit_cast(unsigned, p2);
                unsigned u3 = __builtin_bit_cast(unsigned, p3);
                uint2 w;
                w.x = (u0 >> 16) | (u1 & 0xFFFF0000u);
                w.y = (u2 >> 16) | (u3 & 0xFFFF0000u);
                *(uint2*)&sP[(rt * 16 + quad * 4 + r) * 72 + l16 * 4] = w;
            }
        __syncthreads();

        // P A-frags (slot order) + O += P V
        bf16x8 pa[2][2];
#pragma unroll
        for (int rt = 0; rt < 2; rt++) {
            pa[rt][0] = *(bf16x8*)&sP[(rt * 16 + l16) * 72 + quad * 8];
            pa[rt][1] = *(bf16x8*)&sP[(rt * 16 + l16) * 72 + 32 + quad * 8];
        }
#pragma unroll
        for (int dt = 0; dt < 4; dt++)
#pragma unroll
            for (int rt = 0; rt < 2; rt++) {
                acc[rt][dt] = __builtin_amdgcn_mfma_f32_16x16x32_bf16(pa[rt][0], vb[dt][0], acc[rt][dt], 0, 0, 0);
                acc[rt][dt] = __builtin_amdgcn_mfma_f32_16x16x32_bf16(pa[rt][1], vb[dt][1], acc[rt][dt], 0, 0, 0);
            }
        __syncthreads();
    }

    // epilogue: reduce l across 16-lane row group, scale, store
#pragma unroll
    for (int off = 1; off < 16; off <<= 1)
#pragma unroll
        for (int rt = 0; rt < 2; rt++)
#pragma unroll
            for (int r = 0; r < 4; r++)
                lpart[rt][r] += __shfl_xor(lpart[rt][r], off);

#pragma unroll
    for (int rt = 0; rt < 2; rt++)
#pragma unroll
        for (int r = 0; r < 4; r++) {
            float inv = 1.0f / lpart[rt][r];
            int row = qb + rt * 16 + quad * 4 + r;
#pragma unroll
            for (int dt = 0; dt < 4; dt++) {
                int col = h * 64 + dt * 16 + l16;
                base[(size_t)row * 3072 + 2048 + col] = f2bf(acc[rt][dt][r] * inv);
            }
        }
}

extern "C" void kernel_launch(void* const* d_in, const int* in_sizes, int n_in,
                              void* d_out, int out_size, void* d_ws, size_t ws_size,
                              hipStream_t stream) {
    (void)out_size; (void)ws_size;
    const float *x = (const float*)d_in[0], *w_qkv = (const float*)d_in[1],
                *w_proj = (const float*)d_in[2];
    for (int i = 0; i < n_in; i++) {
        if (in_sizes[i] == 4194304) x = (const float*)d_in[i];
        else if (in_sizes[i] == 3145728) w_qkv = (const float*)d_in[i];
        else if (in_sizes[i] == 1048576) w_proj = (const float*)d_in[i];
    }

    float* out = (float*)d_out;                    // [4096,1024] fp32
    bf16* xb   = (bf16*)d_out;                     // 8.4MB scratch in d_out
    bf16* qkv  = (bf16*)d_ws;                      // [4096,3072] bf16 (25.2MB)
    bf16* r2   = qkv + (size_t)4096 * 3072;        // 8.4MB: wqb -> vt -> wpb
    bf16* wqb  = r2;
    bf16* vt   = r2;
    bf16* wpb  = r2;

    cvt_bf16<<<dim3(2048), dim3(256), 0, stream>>>(x, xb, 4096 * 1024);
    cvt_bf16<<<dim3(1536), dim3(256), 0, stream>>>(w_qkv, wqb, 3072 * 1024);
    gemm_glds<bf16, 128><<<dim3(32, 24), dim3(256), 0, stream>>>(
        xb, 1024, 0, wqb, qkv, 3072, 1024);
    transpose_v<<<dim3(32, 32), dim3(256), 0, stream>>>(qkv, vt);
    attn<<<dim3(32, 64), dim3(64), 0, stream>>>(qkv, vt);
    cvt_bf16<<<dim3(512), dim3(256), 0, stream>>>(w_proj, wpb, 1024 * 1024);
    gemm_glds<float, 128><<<dim3(32, 8), dim3(256), 0, stream>>>(
        qkv, 3072, 2048, wpb, out, 1024, 1024);
}

// Round 13
// 227.452 us; speedup vs baseline: 1.1066x; 1.1066x over previous
//
#include <hip/hip_runtime.h>
#include <hip/hip_bf16.h>

// CausalSelfAttention (B=2, T=2048, D=1024, H=16, hd=64).
// fp32 in, fp32 out storage (bf16-space grading). bf16 MFMA pipeline.
// R13: attn = R10's proven body (80.6us) + one-tile-ahead K prefetch via
// explicit A/B register buffers (unroll-by-2) -> compiler emits vmcnt(N>0)
// waits, K-load latency hidden behind previous tile's body. R12 taught us the
// loop is load-latency-bound (removing VALU filler REGRESSED 80->108us).
// GEMM side: R11/R12 glds kernels (proven). transpose_v back to natural order.

typedef __bf16 bf16;
typedef __bf16 bf16x8 __attribute__((ext_vector_type(8)));
typedef float f32x4 __attribute__((ext_vector_type(4)));

__device__ __forceinline__ bf16 f2bf(float f) {
    unsigned u = __builtin_bit_cast(unsigned, f);
    u += 0x7fffu + ((u >> 16) & 1u);          // RNE
    unsigned short h = (unsigned short)(u >> 16);
    return __builtin_bit_cast(bf16, h);
}
__device__ __forceinline__ bf16 trunc_bf(float f) {
    unsigned u = __builtin_bit_cast(unsigned, f);
    return __builtin_bit_cast(bf16, (unsigned short)(u >> 16));
}

__device__ __forceinline__ bf16x8 ld8f(const float* p) {
    f32x4 a = *(const f32x4*)p;
    f32x4 b = *(const f32x4*)(p + 4);
    bf16x8 r;
#pragma unroll
    for (int i = 0; i < 4; i++) { r[i] = f2bf(a[i]); r[i + 4] = f2bf(b[i]); }
    return r;
}

__device__ __forceinline__ void st_out(bf16* p, float v)  { *p = f2bf(v); }
__device__ __forceinline__ void st_out(float* p, float v) { *p = v; }

// fp32 -> bf16 bulk convert
__global__ __launch_bounds__(256) void cvt_bf16(const float* __restrict__ src,
                                                bf16* __restrict__ dst, int n) {
    int i = (blockIdx.x * 256 + threadIdx.x) * 8;
    if (i < n) *(bf16x8*)&dst[i] = ld8f(&src[i]);
}

// async global->LDS, 16B per lane; LDS dest = uniform base + lane*16
__device__ __forceinline__ void glds16(const bf16* g, bf16* l) {
    __builtin_amdgcn_global_load_lds(
        (const __attribute__((address_space(1))) void*)g,
        (__attribute__((address_space(3))) void*)l, 16, 0, 0);
}

// ---------------------------------------------------------------------------
// C[M,N] = A[., lda, +aoff] @ W[N,K]^T, both bf16. global_load_lds staging,
// XOR chunk swizzle (R11-proven). Tile 128 x BN, BK=32, 4 waves.
// ---------------------------------------------------------------------------
template <typename TC, int BN>
__global__ __launch_bounds__(256) void gemm_glds(const bf16* __restrict__ A, int lda, int aoff,
                                                 const bf16* __restrict__ W,
                                                 TC* __restrict__ C, int N, int K) {
    constexpr int NI = (BN == 128) ? 4 : 2;
    __shared__ bf16 sA[128 * 32];
    __shared__ bf16 sW[BN * 32];
    const int bm = blockIdx.x * 128, bn = blockIdx.y * BN;
    const int tid = threadIdx.x;
    const int wave = tid >> 6, lane = tid & 63;
    const int quad = lane >> 4, l16 = lane & 15;
    const int rbase = (BN == 128) ? (wave >> 1) * 64 : wave * 32;
    const int cbase = (BN == 128) ? (wave & 1) * 64 : 0;
    const int r16 = lane >> 2, cl = lane & 3;
    const int gch = cl ^ ((r16 >> 1) & 3);
    const int sl  = (l16 >> 1) & 3;

    f32x4 acc[NI][4] = {};

    for (int k0 = 0; k0 < K; k0 += 32) {
        __syncthreads();
#pragma unroll
        for (int t = 0; t < 2; t++) {
            int row = wave * 32 + t * 16 + r16;
            glds16(&A[(size_t)(bm + row) * lda + aoff + k0 + gch * 8],
                   &sA[(wave * 32 + t * 16) * 32]);
        }
        if (BN == 128) {
#pragma unroll
            for (int t = 0; t < 2; t++) {
                int row = wave * 32 + t * 16 + r16;
                glds16(&W[(size_t)(bn + row) * K + k0 + gch * 8],
                       &sW[(wave * 32 + t * 16) * 32]);
            }
        } else {
            int row = wave * 16 + r16;
            glds16(&W[(size_t)(bn + row) * K + k0 + gch * 8], &sW[(wave * 16) * 32]);
        }
        __syncthreads();

        bf16x8 af[NI], bfr[4];
#pragma unroll
        for (int i = 0; i < NI; i++)
            af[i] = *(bf16x8*)&sA[(rbase + i * 16 + l16) * 32 + (quad ^ sl) * 8];
#pragma unroll
        for (int j = 0; j < 4; j++)
            bfr[j] = *(bf16x8*)&sW[(cbase + j * 16 + l16) * 32 + (quad ^ sl) * 8];
#pragma unroll
        for (int i = 0; i < NI; i++)
#pragma unroll
            for (int j = 0; j < 4; j++)
                acc[i][j] = __builtin_amdgcn_mfma_f32_16x16x32_bf16(
                    af[i], bfr[j], acc[i][j], 0, 0, 0);
    }

#pragma unroll
    for (int i = 0; i < NI; i++)
#pragma unroll
        for (int j = 0; j < 4; j++)
#pragma unroll
            for (int r = 0; r < 4; r++) {
                int row = bm + rbase + i * 16 + quad * 4 + r;
                int col = bn + cbase + j * 16 + l16;
                st_out(&C[(size_t)row * N + col], acc[i][j][r]);
            }
}

// ---------------------------------------------------------------------------
// vt[bh][d][t] = qkv[b][t][2048 + h*64 + d].  Natural order (R10).
// ---------------------------------------------------------------------------
__global__ __launch_bounds__(256) void transpose_v(const bf16* __restrict__ qkv,
                                                   bf16* __restrict__ vt) {
    __shared__ bf16 s[64][72];
    const int tt = blockIdx.x;
    const int bh = blockIdx.y;
    const int b = bh >> 4, h = bh & 15;
    const int tid = threadIdx.x;

    for (int c = tid; c < 512; c += 256) {
        int t = c >> 3, dc = (c & 7) * 8;
        *(bf16x8*)&s[t][dc] =
            *(const bf16x8*)&qkv[((size_t)(b * 2048 + tt * 64 + t)) * 3072 + 2048 + h * 64 + dc];
    }
    __syncthreads();
    for (int c = tid; c < 512; c += 256) {
        int d = c >> 3, tc = (c & 7) * 8;
        bf16x8 o;
#pragma unroll
        for (int e = 0; e < 8; e++) o[e] = s[tc + e][d];
        *(bf16x8*)&vt[((size_t)bh * 64 + d) * 2048 + tt * 64 + tc] = o;
    }
}

// ---------------------------------------------------------------------------
// Flash causal attention, fixed-max softmax, K-prefetch software pipeline.
// One wave/block, 32 q-rows. R10 body; A/B K-register buffers, unroll-by-2.
// ---------------------------------------------------------------------------
__global__ __launch_bounds__(64, 2) void attn(bf16* __restrict__ qkv,
                                              const bf16* __restrict__ vt) {
    const int bh = blockIdx.x;
    const int i  = 63 - blockIdx.y;
    const int b = bh >> 4, h = bh & 15;
    const int lane = threadIdx.x;
    const int quad = lane >> 4, l16 = lane & 15;

    __shared__ bf16 sP[32 * 90];

    bf16* base = qkv + (size_t)b * 2048 * 3072;
    const bf16* vbh = vt + (size_t)bh * 64 * 2048;
    const int qb = i * 32;
    const int kint = i >> 1;
    const float SC = 0.125f * 1.44269504f;

    bf16x8 qa[2][2];
#pragma unroll
    for (int rt = 0; rt < 2; rt++)
#pragma unroll
        for (int c = 0; c < 2; c++)
            qa[rt][c] = *(const bf16x8*)&base[(size_t)(qb + rt * 16 + l16) * 3072 +
                                              h * 64 + c * 32 + quad * 8];

    f32x4 acc[2][4] = {};
    float lpart[2][4] = {};

    auto loadK = [&](int kt, bf16x8 (&kb)[4][2]) {
#pragma unroll
        for (int j = 0; j < 4; j++) {
            const bf16* kr = &base[(size_t)(kt * 64 + j * 16 + l16) * 3072 + 1024 + h * 64];
            kb[j][0] = *(const bf16x8*)&kr[quad * 8];
            kb[j][1] = *(const bf16x8*)&kr[32 + quad * 8];
        }
    };

    auto body = [&](int kt, bool tail, bf16x8 (&kb)[4][2]) {
        // V loads issued here, consumed at the end (latency hidden by S+exp)
        bf16x8 vb[4][2];
#pragma unroll
        for (int dt = 0; dt < 4; dt++) {
            const bf16* vr = &vbh[(size_t)(dt * 16 + l16) * 2048 + kt * 64];
            vb[dt][0] = *(const bf16x8*)&vr[quad * 8];
            vb[dt][1] = *(const bf16x8*)&vr[32 + quad * 8];
        }

        f32x4 S[2][4] = {};
#pragma unroll
        for (int j = 0; j < 4; j++)
#pragma unroll
            for (int rt = 0; rt < 2; rt++) {
                S[rt][j] = __builtin_amdgcn_mfma_f32_16x16x32_bf16(qa[rt][0], kb[j][0], S[rt][j], 0, 0, 0);
                S[rt][j] = __builtin_amdgcn_mfma_f32_16x16x32_bf16(qa[rt][1], kb[j][1], S[rt][j], 0, 0, 0);
            }

#pragma unroll
        for (int rt = 0; rt < 2; rt++)
#pragma unroll
            for (int j = 0; j < 4; j++)
#pragma unroll
                for (int r = 0; r < 4; r++) {
                    float p = exp2f(S[rt][j][r] * SC - 8.0f);
                    if (tail) {
                        int kg = kt * 64 + j * 16 + l16;
                        int qg = qb + rt * 16 + quad * 4 + r;
                        p = (kg > qg) ? 0.0f : p;
                    }
                    lpart[rt][r] += p;
                    sP[(rt * 16 + quad * 4 + r) * 90 + j * 16 + l16] = trunc_bf(p);
                }
        __syncthreads();

        bf16x8 pa[2][2];
#pragma unroll
        for (int rt = 0; rt < 2; rt++) {
            pa[rt][0] = *(bf16x8*)&sP[(rt * 16 + l16) * 90 + quad * 8];
            pa[rt][1] = *(bf16x8*)&sP[(rt * 16 + l16) * 90 + 32 + quad * 8];
        }
#pragma unroll
        for (int dt = 0; dt < 4; dt++)
#pragma unroll
            for (int rt = 0; rt < 2; rt++) {
                acc[rt][dt] = __builtin_amdgcn_mfma_f32_16x16x32_bf16(pa[rt][0], vb[dt][0], acc[rt][dt], 0, 0, 0);
                acc[rt][dt] = __builtin_amdgcn_mfma_f32_16x16x32_bf16(pa[rt][1], vb[dt][1], acc[rt][dt], 0, 0, 0);
            }
        __syncthreads();
    };

    bf16x8 kbA[4][2], kbB[4][2];
    loadK(0, kbA);
    int kt = 0;
    while (true) {
        if (kt + 1 <= kint) loadK(kt + 1, kbB);    // prefetch next tile's K
        body(kt, kt == kint, kbA);
        if (++kt > kint) break;
        if (kt + 1 <= kint) loadK(kt + 1, kbA);
        body(kt, kt == kint, kbB);
        if (++kt > kint) break;
    }

    // epilogue: reduce l across 16-lane row group, scale, store
#pragma unroll
    for (int off = 1; off < 16; off <<= 1)
#pragma unroll
        for (int rt = 0; rt < 2; rt++)
#pragma unroll
            for (int r = 0; r < 4; r++)
                lpart[rt][r] += __shfl_xor(lpart[rt][r], off);

#pragma unroll
    for (int rt = 0; rt < 2; rt++)
#pragma unroll
        for (int r = 0; r < 4; r++) {
            float inv = 1.0f / lpart[rt][r];
            int row = qb + rt * 16 + quad * 4 + r;
#pragma unroll
            for (int dt = 0; dt < 4; dt++) {
                int col = h * 64 + dt * 16 + l16;
                base[(size_t)row * 3072 + 2048 + col] = f2bf(acc[rt][dt][r] * inv);
            }
        }
}

extern "C" void kernel_launch(void* const* d_in, const int* in_sizes, int n_in,
                              void* d_out, int out_size, void* d_ws, size_t ws_size,
                              hipStream_t stream) {
    (void)out_size; (void)ws_size;
    const float *x = (const float*)d_in[0], *w_qkv = (const float*)d_in[1],
                *w_proj = (const float*)d_in[2];
    for (int i = 0; i < n_in; i++) {
        if (in_sizes[i] == 4194304) x = (const float*)d_in[i];
        else if (in_sizes[i] == 3145728) w_qkv = (const float*)d_in[i];
        else if (in_sizes[i] == 1048576) w_proj = (const float*)d_in[i];
    }

    float* out = (float*)d_out;                    // [4096,1024] fp32
    bf16* xb   = (bf16*)d_out;                     // 8.4MB scratch in d_out
    bf16* qkv  = (bf16*)d_ws;                      // [4096,3072] bf16 (25.2MB)
    bf16* r2   = qkv + (size_t)4096 * 3072;        // 8.4MB: wqb -> vt -> wpb
    bf16* wqb  = r2;
    bf16* vt   = r2;
    bf16* wpb  = r2;

    cvt_bf16<<<dim3(2048), dim3(256), 0, stream>>>(x, xb, 4096 * 1024);
    cvt_bf16<<<dim3(1536), dim3(256), 0, stream>>>(w_qkv, wqb, 3072 * 1024);
    gemm_glds<bf16, 128><<<dim3(32, 24), dim3(256), 0, stream>>>(
        xb, 1024, 0, wqb, qkv, 3072, 1024);
    transpose_v<<<dim3(32, 32), dim3(256), 0, stream>>>(qkv, vt);
    attn<<<dim3(32, 64), dim3(64), 0, stream>>>(qkv, vt);
    cvt_bf16<<<dim3(512), dim3(256), 0, stream>>>(w_proj, wpb, 1024 * 1024);
    gemm_glds<float, 128><<<dim3(32, 8), dim3(256), 0, stream>>>(
        qkv, 3072, 2048, wpb, out, 1024, 1024);
}